// Round 15
// baseline (1584.018 us; speedup 1.0000x reference)
//
#include <hip/hip_runtime.h>
#include <math.h>

namespace {

constexpr int B = 8, T = 10, C = 32, H = 128, W = 128;
constexpr int HW = H * W;            // 16384
constexpr int CHW = C * HW;          // 524288
constexpr int BHW = B * HW;
constexpr long long NSTATE = (long long)B * CHW;

constexpr float DF = 0.90483741803595952f;  // exp(-0.1)
constexpr float DL = 0.36787944117144233f;  // exp(-1.0)
constexpr float DE = 0.36787944117144233f;  // exp(-1.0)
constexpr float VE = 10.0f;
constexpr float E0 = 3.6787944117144233f;   // DE * (V_E/ALPHA_E), e-fold init

// wgt[co][ci][kh][kw] -> wtr[ci][k][co]   (9216 floats)
__global__ void k_wtr(const float* __restrict__ wgt, float* __restrict__ wtr) {
  int i = blockIdx.x * 256 + threadIdx.x;
  if (i >= C * C * 9) return;
  int ci = i / 288;
  int k = (i / 32) % 9;
  int co = i & 31;
  wtr[i] = wgt[co * 288 + ci * 9 + k];
}

// t=0: y_prev=0 -> conv=0, l=0, u=f. Writes f, e_used(1), out[0], l-plane.
__launch_bounds__(256, 2)
__global__ void k_step0(const float* __restrict__ x, const float* __restrict__ bias,
                        float* __restrict__ f, float* __restrict__ e,
                        float* __restrict__ lpl, float* __restrict__ out) {
  const int tid = threadIdx.x, bid = blockIdx.x;
  const int wg = (bid & 7) * 128 + (bid >> 3);  // XCD swizzle
  const int tw = wg & 7, th = (wg >> 3) & 15, b = wg >> 7;
  const int h0 = th * 8, w0 = tw * 16;
  const int g = tid >> 5, s = tid & 31;
  const int sh = s >> 2, sw = s & 3, cb = 4 * sw;
  const int gh = h0 + sh, gwc = w0 + cb;
  const float4 bc4 = *(const float4*)&bias[4 * g];
  const float bc[4] = {bc4.x, bc4.y, bc4.z, bc4.w};

#pragma unroll
  for (int q = 0; q < 4; ++q) {
    const int c = 4 * g + q;
    const size_t sidx = (size_t)b * CHW + (size_t)c * HW + (size_t)gh * W + gwc;
    const size_t oidx = (((size_t)b * T) * C + c) * (size_t)HW + (size_t)gh * W + gwc;
    float4 x4 = *(const float4*)(x + oidx);
    float xr[4] = {x4.x, x4.y, x4.z, x4.w};
    float fo[4], eo[4], yn[4];
#pragma unroll
    for (int p = 0; p < 4; ++p) {
      float fn = bc[q] + xr[p];                  // DF*0 + conv(0) + bias + x
      float yy = 1.f / (1.f + __expf(E0 - fn));  // u = fn (l=0)
      fo[p] = fn;
      eo[p] = DE * E0 + VE * yy;                 // e_used(1)
      yn[p] = yy;
    }
    *(float4*)(f + sidx) = make_float4(fo[0], fo[1], fo[2], fo[3]);
    *(float4*)(e + sidx) = make_float4(eo[0], eo[1], eo[2], eo[3]);
    *(float4*)(out + oidx) = make_float4(yn[0], yn[1], yn[2], yn[3]);
  }
  if (tid < 32) {
    const size_t pidx = (size_t)b * HW + (size_t)gh * W + gwc;
    *(float4*)(lpl + pidx) = make_float4(0.f, 0.f, 0.f, 0.f);  // l_1 = 0
  }
}

// Steps 1..T-1. 1024 blocks x 256 threads (4 blocks/CU), tile 8x16.
// Wave = co-group (8 c_out, wave-uniform): weights via SCALAR loads from
// global wtr (no LDS, no bank conflicts, FMA = v_fmac(sgpr, vgpr)).
// Lane = 2-px strip: acc[8][2] = 16 regs (R12's proven budget).
// y: double-buffered LDS, 1 barrier/chunk, depth-1 register prefetch.
// Chansum from staged y tile (no s planes). Early f/e loads at chunk 3.
__launch_bounds__(256, 2)
__global__ void k_step(const float* __restrict__ x, const float* __restrict__ wtr,
                       const float* __restrict__ bias, float* __restrict__ f,
                       float* __restrict__ e, float* __restrict__ lpl,
                       float* __restrict__ out, int t) {
  __shared__ float ysl[2][8][10][28];  // [buf][ci][row][slot] slot=w-(w0-4); 17.9KB
  __shared__ float sl[10][21];         // chansum tile (+halo)

  const int tid = threadIdx.x, bid = blockIdx.x;
  const int wg = (bid & 7) * 128 + (bid >> 3);  // XCD swizzle: batch per XCD
  const int tw = wg & 7, th = (wg >> 3) & 15, b = wg >> 7;
  const int h0 = th * 8, w0 = tw * 16;
  const int s = tid & 63;
  const int sh = s >> 3, sw = s & 7, cb = 2 * sw;   // 2-px strip
  const int gh = h0 + sh, gwc = w0 + cb;
  const int cob = __builtin_amdgcn_readfirstlane((tid >> 6) * 8);  // wave co-base

  const float* ybase = out + ((size_t)b * T + (t - 1)) * CHW;

  // l-plane read (channel-uniform), 2 px
  float2 l2 = *(const float2*)(lpl + (size_t)b * HW + (size_t)gh * W + gwc);
  float lold[2] = {l2.x, l2.y};

  // y-prefetch slots (chunk-invariant address parts). 480 float4 per chunk.
  const int i0 = tid;                                  // slot 0: always valid
  const int cil0 = i0 / 60, rr0 = (i0 % 60) / 6, j0 = i0 % 6;
  const int gh0p = h0 - 1 + rr0, ws0p = w0 - 4 + 4 * j0;
  const bool ok0 = (unsigned)gh0p < (unsigned)H && (unsigned)ws0p <= (unsigned)(W - 4);
  const size_t yoff0 = (size_t)cil0 * HW + (size_t)(ok0 ? gh0p * W + ws0p : 0);
  const int i1 = tid + 256;                            // slot 1: valid if <480
  const bool use1 = i1 < 480;
  const int cil1 = (i1 / 60) & 7, rr1 = (i1 % 60) / 6, j1 = i1 % 6;
  const int gh1p = h0 - 1 + rr1, ws1p = w0 - 4 + 4 * j1;
  const bool ok1 = use1 && (unsigned)gh1p < (unsigned)H &&
                   (unsigned)ws1p <= (unsigned)(W - 4);
  const size_t yoff1 = (size_t)cil1 * HW + (size_t)(ok1 ? gh1p * W + ws1p : 0);

  float4 y0v, y1v;
  auto prefetch = [&](int cc) {
    const float* yb = ybase + (size_t)cc * 8 * HW;
    y0v = ok0 ? *(const float4*)(yb + yoff0) : make_float4(0.f, 0.f, 0.f, 0.f);
    y1v = ok1 ? *(const float4*)(yb + yoff1) : make_float4(0.f, 0.f, 0.f, 0.f);
  };
  auto commit = [&](int nb) {  // rows 112B: 16B-aligned float4 stores
    *(float4*)&ysl[nb][cil0][rr0][4 * j0] = y0v;
    if (use1) *(float4*)&ysl[nb][cil1][rr1][4 * j1] = y1v;
  };

  prefetch(0);
  commit(0);
  prefetch(1);
  __syncthreads();  // buf0 visible

  float acc[8][2] = {};
  float scol = 0.f;  // chansum accumulator (tid<180)
  const int srr = tid / 18, scl = tid % 18;
  const bool hasS = tid < 180;
  float2 fq2[8], eq2[8];

#pragma unroll 1
  for (int cc = 0; cc < 4; ++cc) {
    const int nb = cc & 1;
    if (cc == 3) {  // prefetch regs dead: early f/e loads hide under last conv
#pragma unroll
      for (int q = 0; q < 8; ++q) {
        const size_t sidx =
            (size_t)b * CHW + (size_t)(cob + q) * HW + (size_t)gh * W + gwc;
        fq2[q] = *(const float2*)(f + sidx);
        eq2[q] = *(const float2*)(e + sidx);
      }
    }
#pragma unroll
    for (int ci = 0; ci < 8; ++ci) {
      // 4-float window (2 px + halo): 3 x b64 per row
      float yr[3][4];
#pragma unroll
      for (int kh = 0; kh < 3; ++kh) {
        const float* rowp = &ysl[nb][ci][sh + kh][0];
        float2 r0 = *(const float2*)(rowp + cb + 2);  // slots cb+2,cb+3
        float2 r1 = *(const float2*)(rowp + cb + 4);  // slots cb+4,cb+5
        float2 r2 = *(const float2*)(rowp + cb + 6);  // slots cb+6,cb+7
        yr[kh][0] = r0.y; yr[kh][1] = r1.x; yr[kh][2] = r1.y; yr[kh][3] = r2.x;
      }
      // weights: wave-uniform global addresses -> scalar loads
      const float* wci = wtr + (size_t)(cc * 8 + ci) * 288 + cob;
#pragma unroll
      for (int k = 0; k < 9; ++k) {
        const int kh = k / 3, kw = k % 3;
        float4 wa = *(const float4*)(wci + k * 32);      // s_load (uniform)
        float4 wb = *(const float4*)(wci + k * 32 + 4);  // s_load (uniform)
        const float wq[8] = {wa.x, wa.y, wa.z, wa.w, wb.x, wb.y, wb.z, wb.w};
#pragma unroll
        for (int q = 0; q < 8; ++q)
#pragma unroll
          for (int p = 0; p < 2; ++p)
            acc[q][p] = fmaf(wq[q], yr[kh][p + kw], acc[q][p]);
      }
    }
    // chansum rides the staged chunk
    if (hasS) {
      const float* yb = &ysl[nb][0][srr][scl + 3];
#pragma unroll
      for (int ci = 0; ci < 8; ++ci) scol += yb[ci * 280];
    }
    if (cc < 3) {
      commit(nb ^ 1);                // regs prefetched one chunk ago
      if (cc < 2) prefetch(cc + 2);  // depth-1 in flight
      __syncthreads();               // one barrier per chunk
    }
  }

  // finalize chansum tile, then l-inc
  if (hasS) sl[srr][scl] = scol;
  __syncthreads();
  float lnew[2];
#pragma unroll
  for (int p = 0; p < 2; ++p) {
    const int c0 = cb + p;
    float linc =
        0.5f * (sl[sh][c0] + sl[sh][c0 + 2] + sl[sh + 2][c0] + sl[sh + 2][c0 + 2]) +
        sl[sh][c0 + 1] + sl[sh + 2][c0 + 1] + sl[sh + 1][c0] + sl[sh + 1][c0 + 2];
    lnew[p] = DL * lold[p] + linc;
  }

  // epilogue: f/e update (e-fold), out write; 8 co x 2 px per thread
  const float4 bcA = *(const float4*)&bias[cob];      // uniform -> s_load
  const float4 bcB = *(const float4*)&bias[cob + 4];
  const float bc[8] = {bcA.x, bcA.y, bcA.z, bcA.w, bcB.x, bcB.y, bcB.z, bcB.w};
#pragma unroll
  for (int q = 0; q < 8; ++q) {
    const int c = cob + q;
    const size_t sidx = (size_t)b * CHW + (size_t)c * HW + (size_t)gh * W + gwc;
    const size_t oidx = (((size_t)b * T + t) * C + c) * (size_t)HW + (size_t)gh * W + gwc;
    float2 x2 = *(const float2*)(x + oidx);
    float fr[2] = {fq2[q].x, fq2[q].y};
    float er[2] = {eq2[q].x, eq2[q].y};
    float xr[2] = {x2.x, x2.y};
    float fo[2], eo[2], yn[2];
#pragma unroll
    for (int p = 0; p < 2; ++p) {
      float fn = DF * fr[p] + acc[q][p] + bc[q] + xr[p];
      float u = fmaf(0.5f * fn, lnew[p], fn);
      float yy = 1.f / (1.f + __expf(er[p] - u));
      fo[p] = fn;
      eo[p] = DE * er[p] + VE * yy;  // e_used(t+1)
      yn[p] = yy;
    }
    *(float2*)(f + sidx) = make_float2(fo[0], fo[1]);
    *(float2*)(e + sidx) = make_float2(eo[0], eo[1]);
    *(float2*)(out + oidx) = make_float2(yn[0], yn[1]);
  }
  if (tid < 64) {  // wave 0 spans the whole 8x16 tile: store l-plane
    const size_t pidx = (size_t)b * HW + (size_t)gh * W + gwc;
    *(float2*)(lpl + pidx) = make_float2(lnew[0], lnew[1]);
  }
}

}  // namespace

extern "C" void kernel_launch(void* const* d_in, const int* in_sizes, int n_in,
                              void* d_out, int out_size, void* d_ws, size_t ws_size,
                              hipStream_t stream) {
  (void)in_sizes; (void)n_in; (void)out_size; (void)ws_size;
  const float* x = (const float*)d_in[0];     // (B,T,C,H,W)
  const float* wgt = (const float*)d_in[1];   // (C,C,3,3)
  const float* bias = (const float*)d_in[2];  // (C,)
  float* out = (float*)d_out;                 // (B,T,C,H,W)

  float* ws = (float*)d_ws;
  float* f = ws;                    // NSTATE
  float* e = f + NSTATE;            // NSTATE
  float* lpl = e + NSTATE;          // BHW (l is channel-uniform)
  float* wtr = lpl + BHW;           // 9216

  k_wtr<<<36, 256, 0, stream>>>(wgt, wtr);
  k_step0<<<1024, 256, 0, stream>>>(x, bias, f, e, lpl, out);

  for (int t = 1; t < T; ++t) {
    k_step<<<1024, 256, 0, stream>>>(x, wtr, bias, f, e, lpl, out, t);
  }
}